// Round 10
// baseline (406.420 us; speedup 1.0000x reference)
//
#include <hip/hip_runtime.h>
#include <hip/hip_fp16.h>

#define NN 50000
#define NE 1600000
#define DD 128
#define NH 9
#define NC 8
#define HCH 72
#define NEG 0.2f
#define NBUCK 196      // ceil(50000/256), 256 dst nodes per bucket
#define NSEG 16        // src segments of 4096 nodes (only 0..12 non-empty)
#define SPAD 17        // padded seg stride in k_scat2 LDS (bank-conflict fix)
#define EPB 16         // edges per thread in bin part
#define BCH (256*EPB)  // 4096 edges per bin block
#define BSTRIDE 10240  // fixed per-bucket capacity (mean 8192, sigma 90 -> +22 sigma)
#define BCSTRIDE 16    // bcursor padded to 64B/bucket
#define GEMMB2 ((NN + 63) / 64)          // 782 mfma-gemm blocks (64 nodes each)
#define BINB ((NE + BCH - 1) / BCH)      // 391 bin blocks
#define AGGB ((NN * NH + 255) / 256)     // 1758 agg blocks per graph
#define CLP 88         // padded col-stride of C LDS tile (fp16)

typedef _Float16 f16x8 __attribute__((ext_vector_type(8)));
typedef float f32x4 __attribute__((ext_vector_type(4)));

__device__ __forceinline__ unsigned short f2h(float f) {
  return __half_as_ushort(__float2half_rn(f));
}
__device__ __forceinline__ float h2f(unsigned short u) {
  return __half2float(__ushort_as_half(u));
}
__device__ __forceinline__ float hlo(unsigned u) {
  return __half2float(__ushort_as_half((unsigned short)(u & 0xFFFFu)));
}
__device__ __forceinline__ float hhi(unsigned u) {
  return __half2float(__ushort_as_half((unsigned short)(u >> 16)));
}

struct GP {
  const float* x; const int* ei; const float* W;
  const float* as; const float* ad; const float* b;
  uint4* h2;                // [NN*9] uint4: 8 fp16 channels per (node,head)
  unsigned short* as2;      // [NN*9] fp16 src-attention scores
  float* a_d; float* out;
  _Float16* wf;             // [4*5*64*8] fragment-ordered fp16 W (20KB, k_wpack)
  int* offs2;               // [NBUCK*256*16] per-(node,seg) absolute csr offsets
  int* bcursor;             // [NBUCK*BCSTRIDE] bucket fill counts (64B-padded, atomic)
  unsigned int* pairs;      // [NBUCK*BSTRIDE] strided bucket runs
  int* csr;                 // [NBUCK*BSTRIDE]
};
struct GT { GP g[3]; };

// one gathered edge -> softmax weight + weighted h accumulate
__device__ __forceinline__ void accum(unsigned short u, uint4 v, float ad_n,
                                      float& denom, float4& acc0, float4& acc1) {
  float tt = h2f(u) + ad_n;
  tt = (tt > 0.f) ? tt : NEG * tt;
  const float w = __expf(tt);
  denom += w;
  acc0.x = fmaf(w, hlo(v.x), acc0.x); acc0.y = fmaf(w, hhi(v.x), acc0.y);
  acc0.z = fmaf(w, hlo(v.y), acc0.z); acc0.w = fmaf(w, hhi(v.y), acc0.w);
  acc1.x = fmaf(w, hlo(v.z), acc1.x); acc1.y = fmaf(w, hhi(v.z), acc1.y);
  acc1.z = fmaf(w, hlo(v.w), acc1.z); acc1.w = fmaf(w, hhi(v.w), acc1.w);
}

// Pre-pack W into MFMA B-fragment order, fp16, ONCE per graph.
// wf[((ks*5+ct)*64+lane)*8+j] = fp16(W[ks*32+(lane>>4)*8+j][ct*16+(lane&15)])
__global__ __launch_bounds__(256) void k_wpack(GT t) {
  const GP G = t.g[blockIdx.z];
  const int tid = threadIdx.x;
  for (int idx = tid; idx < 4 * 5 * 64 * 8; idx += 256) {
    const int j = idx & 7;
    const int lane = (idx >> 3) & 63;
    const int ctks = idx >> 9;           // 0..19
    const int ct = ctks % 5;
    const int ks = ctks / 5;
    const int k = ks * 32 + ((lane >> 4) << 3) + j;
    const int col = ct * 16 + (lane & 15);
    const float v = (col < HCH) ? G.W[k * HCH + col] : 0.f;
    G.wf[idx] = (_Float16)v;
  }
}

// Fused bin + gemm (independent stages re-converged so bin's 391 long-pole
// latency blocks (1.5/CU alone) overlap gemm's 782 compute blocks).
// x < BINB: bin edges into fixed-stride bucket runs (LDS sort, coalesced out).
// x >= BINB: h = x@W via MFMA fp16 with pre-packed wf (L2-broadcast B-frags).
__global__ __launch_bounds__(256) void k_fat(GT t) {
  const GP G = t.g[blockIdx.z];
  __shared__ __align__(16) char smem[23072];   // union: bin 23.0KB / gemm 11.3KB
  const int tid = threadIdx.x;

  if (blockIdx.x < BINB) {
    // ---- bin part ----
    unsigned* stage = (unsigned*)smem;                       // 16384 B
    unsigned char* bkt = (unsigned char*)(smem + 16384);     // 4096 B
    int* hist   = (int*)(smem + 20480);                      // 784 B
    int* gdelta = (int*)(smem + 21264);                      // 784 B
    int* ssum   = (int*)(smem + 22048);                      // 1024 B
    const int e0 = blockIdx.x * BCH;

    for (int i = tid; i < NBUCK; i += 256) hist[i] = 0;
    __syncthreads();
    int dsts[EPB], srcs[EPB];
    #pragma unroll
    for (int k = 0; k < EPB; ++k) {
      const int e = e0 + k * 256 + tid;
      if (e < NE) {
        dsts[k] = G.ei[NE + e];
        srcs[k] = G.ei[e];
        atomicAdd(&hist[dsts[k] >> 8], 1);
      } else dsts[k] = -1;
    }
    __syncthreads();
    // exclusive scan over the 196 bucket counts (Hillis-Steele, 256 threads)
    const int cnt_t = (tid < NBUCK) ? hist[tid] : 0;
    ssum[tid] = cnt_t;
    __syncthreads();
    int run = cnt_t;
    for (int off = 1; off < 256; off <<= 1) {
      int u = (tid >= off) ? ssum[tid - off] : 0;
      __syncthreads();
      run += u;
      ssum[tid] = run;
      __syncthreads();
    }
    const int excl = run - cnt_t;
    if (tid < NBUCK) {
      const int gbase = cnt_t ? atomicAdd(&G.bcursor[tid * BCSTRIDE], cnt_t) : 0;
      gdelta[tid] = tid * BSTRIDE + gbase - excl;
      hist[tid] = excl;                  // counts dead; reuse as scatter cursors
    }
    __syncthreads();
    #pragma unroll
    for (int k = 0; k < EPB; ++k) {
      if (dsts[k] >= 0) {
        const int b = dsts[k] >> 8;
        const int pos = atomicAdd(&hist[b], 1);
        stage[pos] = (unsigned)srcs[k] | ((unsigned)(dsts[k] & 255) << 16);
        bkt[pos] = (unsigned char)b;
      }
    }
    __syncthreads();
    const int total = (e0 + BCH <= NE) ? BCH : (NE - e0);
    for (int i = tid; i < total; i += 256) {
      const int b = bkt[i];
      const int addr = gdelta[b] + i;    // = b*BSTRIDE + gbase + (i - lstart[b])
      if (addr - b * BSTRIDE < BSTRIDE)  // overflow guard (effectively never)
        G.pairs[addr] = stage[i];
    }
    return;
  }

  // ---- gemm part ----
  _Float16* Cl = (_Float16*)smem;                      // [64][CLP] 11264 B
  const int wv = tid >> 6;       // wave 0..3 -> rows wv*16..wv*16+15
  const int ln = tid & 63;
  const int rl = ln & 15;        // A row within 16 / B col within 16
  const int kg = ln >> 4;        // k-group 0..3 (8 consecutive k each)
  const int n0 = (blockIdx.x - BINB) << 6;
  int arow = n0 + wv * 16 + rl;
  if (arow >= NN) arow = NN - 1;            // clamp: loads stay in-bounds, stores guarded
  const float4* xr = (const float4*)(G.x + (size_t)arow * DD) + (kg << 1);
  const f16x8* wfp = (const f16x8*)G.wf;

  f32x4 acc[5];
  #pragma unroll
  for (int ct = 0; ct < 5; ++ct) acc[ct] = (f32x4){0.f, 0.f, 0.f, 0.f};

  #pragma unroll
  for (int ks = 0; ks < 4; ++ks) {
    const float4 xa = xr[ks * 8];           // floats kg*8 + ks*32 .. +3
    const float4 xb = xr[ks * 8 + 1];       // .. +7
    float xs[8] = {xa.x, xa.y, xa.z, xa.w, xb.x, xb.y, xb.z, xb.w};
    f16x8 ahi, alo;
    #pragma unroll
    for (int j = 0; j < 8; ++j) {
      const _Float16 h = (_Float16)xs[j];
      ahi[j] = h;
      alo[j] = (_Float16)(xs[j] - (float)h);   // residual: near-fp32 A path
    }
    #pragma unroll
    for (int ct = 0; ct < 5; ++ct) {
      const f16x8 bf = wfp[(ks * 5 + ct) * 64 + ln];
      acc[ct] = __builtin_amdgcn_mfma_f32_16x16x32_f16(ahi, bf, acc[ct], 0, 0, 0);
      acc[ct] = __builtin_amdgcn_mfma_f32_16x16x32_f16(alo, bf, acc[ct], 0, 0, 0);
    }
  }

  // C/D layout (HW-verified): col = lane&15, row = (lane>>4)*4 + reg
  #pragma unroll
  for (int ct = 0; ct < 5; ++ct) {
    #pragma unroll
    for (int j = 0; j < 4; ++j)
      Cl[(wv * 16 + kg * 4 + j) * CLP + ct * 16 + rl] = (_Float16)acc[ct][j];
  }
  __syncthreads();

  // epilogue: per (node,head) pair, h2 is the packed uint4 straight from LDS
  for (int p = tid; p < 64 * NH; p += 256) {
    const int node = p / NH;
    const int hd = p - node * NH;
    const int n = n0 + node;
    if (n >= NN) continue;
    const uint4 hv = *(const uint4*)&Cl[node * CLP + hd * NC];
    const float h0 = hlo(hv.x), h1 = hhi(hv.x), h2v = hlo(hv.y), h3 = hhi(hv.y);
    const float h4 = hlo(hv.z), h5 = hhi(hv.z), h6 = hlo(hv.w), h7 = hhi(hv.w);
    const float4 As0 = *(const float4*)(G.as + hd * NC);
    const float4 As1 = *(const float4*)(G.as + hd * NC + 4);
    const float4 Ad0 = *(const float4*)(G.ad + hd * NC);
    const float4 Ad1 = *(const float4*)(G.ad + hd * NC + 4);
    const float ssrc = h0 * As0.x + h1 * As0.y + h2v * As0.z + h3 * As0.w
                     + h4 * As1.x + h5 * As1.y + h6 * As1.z + h7 * As1.w;
    const float sdst = h0 * Ad0.x + h1 * Ad0.y + h2v * Ad0.z + h3 * Ad0.w
                     + h4 * Ad1.x + h5 * Ad1.y + h6 * Ad1.z + h7 * Ad1.w;
    G.h2[(size_t)n * NH + hd] = hv;
    G.as2[n * NH + hd] = f2h(ssrc);
    G.a_d[n * NH + hd] = sdst;
  }
}

// One block per bucket. LDS counting sort with key (dst_local,seg); sorted
// src values staged in LDS ushort, then coalesced copy-out to csr.
__global__ __launch_bounds__(256) void k_scat2(GT t) {
  const GP G = t.g[blockIdx.z];
  const int b = blockIdx.x;
  const int d0 = b << 8;
  __shared__ int cnt[256 * SPAD];            // 17.4 KB (counts, then LOCAL cursors)
  __shared__ int ssum[256];
  __shared__ unsigned short stage[BSTRIDE];  // 20.5 KB sorted src values
  const int tid = threadIdx.x;
  const int estart = b * BSTRIDE;
  const int count0 = G.bcursor[b * BCSTRIDE];
  const int count = (count0 < BSTRIDE) ? count0 : BSTRIDE;   // clamp (never in practice)
  const int eend = estart + count;
  for (int i = tid; i < 256 * SPAD; i += 256) cnt[i] = 0;
  __syncthreads();
  for (int e = estart + tid; e < eend; e += 256) {
    unsigned p = G.pairs[e];
    int key = (int)((p >> 16) * SPAD + ((p & 0xFFFFu) >> 12));
    atomicAdd(&cnt[key], 1);
  }
  __syncthreads();
  int local[NSEG];
  int sum = 0;
  #pragma unroll
  for (int i = 0; i < NSEG; ++i) { local[i] = sum; sum += cnt[tid * SPAD + i]; }
  ssum[tid] = sum;
  __syncthreads();
  int run = sum;
  for (int off = 1; off < 256; off <<= 1) {
    int u = (tid >= off) ? ssum[tid - off] : 0;
    __syncthreads();
    run += u;
    ssum[tid] = run;
    __syncthreads();
  }
  const int texcl = run - sum;
  int* o2 = G.offs2 + ((size_t)d0 << 4);
  #pragma unroll
  for (int i = 0; i < NSEG; ++i) {
    const int v = texcl + local[i];         // bucket-LOCAL offset
    cnt[tid * SPAD + i] = v;                // counts dead; reuse as local cursors
    o2[tid * NSEG + i] = estart + v;        // offs2 stays ABSOLUTE
  }
  __syncthreads();
  for (int e = estart + tid; e < eend; e += 256) {
    unsigned p = G.pairs[e];
    int key = (int)((p >> 16) * SPAD + ((p & 0xFFFFu) >> 12));
    int lpos = atomicAdd(&cnt[key], 1);
    if (lpos < BSTRIDE)
      stage[lpos] = (unsigned short)(p & 0xFFFFu);
  }
  __syncthreads();
  // coalesced copy-out: dense sequential 4B stores -> full-line writebacks
  for (int i = tid; i < count; i += 256)
    G.csr[estart + i] = (int)stage[i];
}

// gather aggregation: thread (dst,head). All 3 graphs fused, graph-major.
// R10 changes: (a) 8-edge batching (mean list/sgrp ~8 -> one batch covers it,
// doubles memory-level parallelism); (b) per-sgrp barrier is a RAW s_barrier —
// k_agg has no LDS, the barrier is pure wave phase-alignment for L2 locality,
// so the compiler's vmcnt(0) drain that __syncthreads() forces is waste.
__global__ __launch_bounds__(256) void k_agg(GT t) {
  const int g = blockIdx.x / AGGB;
  const GP G = t.g[g];
  const int gid = (blockIdx.x - g * AGGB) * 256 + threadIdx.x;
  const bool active = (gid < NN * NH);
  int n = 0, head = 0;
  if (active) { n = gid / NH; head = gid - n * NH; }
  float denom = 0.f;
  float4 acc0 = make_float4(0.f, 0.f, 0.f, 0.f);
  float4 acc1 = make_float4(0.f, 0.f, 0.f, 0.f);
  float ad_n = 0.f;
  int gb[5] = {0, 0, 0, 0, 0};
  if (active) {
    ad_n = G.a_d[n * NH + head];
    const int* o2 = G.offs2 + ((size_t)n << 4);
    gb[0] = o2[0]; gb[1] = o2[4]; gb[2] = o2[8]; gb[3] = o2[12]; gb[4] = o2[13];
    float sl = h2f(G.as2[n * NH + head]) + ad_n;
    sl = (sl > 0.f) ? sl : NEG * sl;
    float wl = __expf(sl);
    uint4 hs = G.h2[(size_t)n * NH + head];
    denom = wl;
    acc0.x = wl * hlo(hs.x); acc0.y = wl * hhi(hs.x);
    acc0.z = wl * hlo(hs.y); acc0.w = wl * hhi(hs.y);
    acc1.x = wl * hlo(hs.z); acc1.y = wl * hhi(hs.z);
    acc1.z = wl * hlo(hs.w); acc1.w = wl * hhi(hs.w);
  }
  #pragma unroll
  for (int sgrp = 0; sgrp < 4; ++sgrp) {
    int e = gb[sgrp];
    const int en = gb[sgrp + 1];
    for (; e + 8 <= en; e += 8) {
      const int s0 = G.csr[e];
      const int s1 = G.csr[e + 1];
      const int s2 = G.csr[e + 2];
      const int s3 = G.csr[e + 3];
      const int s4 = G.csr[e + 4];
      const int s5 = G.csr[e + 5];
      const int s6 = G.csr[e + 6];
      const int s7 = G.csr[e + 7];
      const unsigned short u0 = G.as2[s0 * NH + head];
      const unsigned short u1 = G.as2[s1 * NH + head];
      const unsigned short u2 = G.as2[s2 * NH + head];
      const unsigned short u3 = G.as2[s3 * NH + head];
      const unsigned short u4 = G.as2[s4 * NH + head];
      const unsigned short u5 = G.as2[s5 * NH + head];
      const unsigned short u6 = G.as2[s6 * NH + head];
      const unsigned short u7 = G.as2[s7 * NH + head];
      const uint4 v0 = G.h2[(size_t)s0 * NH + head];
      const uint4 v1 = G.h2[(size_t)s1 * NH + head];
      const uint4 v2 = G.h2[(size_t)s2 * NH + head];
      const uint4 v3 = G.h2[(size_t)s3 * NH + head];
      const uint4 v4 = G.h2[(size_t)s4 * NH + head];
      const uint4 v5 = G.h2[(size_t)s5 * NH + head];
      const uint4 v6 = G.h2[(size_t)s6 * NH + head];
      const uint4 v7 = G.h2[(size_t)s7 * NH + head];
      accum(u0, v0, ad_n, denom, acc0, acc1);
      accum(u1, v1, ad_n, denom, acc0, acc1);
      accum(u2, v2, ad_n, denom, acc0, acc1);
      accum(u3, v3, ad_n, denom, acc0, acc1);
      accum(u4, v4, ad_n, denom, acc0, acc1);
      accum(u5, v5, ad_n, denom, acc0, acc1);
      accum(u6, v6, ad_n, denom, acc0, acc1);
      accum(u7, v7, ad_n, denom, acc0, acc1);
    }
    if (e + 4 <= en) {
      const int s0 = G.csr[e];
      const int s1 = G.csr[e + 1];
      const int s2 = G.csr[e + 2];
      const int s3 = G.csr[e + 3];
      const unsigned short u0 = G.as2[s0 * NH + head];
      const unsigned short u1 = G.as2[s1 * NH + head];
      const unsigned short u2 = G.as2[s2 * NH + head];
      const unsigned short u3 = G.as2[s3 * NH + head];
      const uint4 v0 = G.h2[(size_t)s0 * NH + head];
      const uint4 v1 = G.h2[(size_t)s1 * NH + head];
      const uint4 v2 = G.h2[(size_t)s2 * NH + head];
      const uint4 v3 = G.h2[(size_t)s3 * NH + head];
      accum(u0, v0, ad_n, denom, acc0, acc1);
      accum(u1, v1, ad_n, denom, acc0, acc1);
      accum(u2, v2, ad_n, denom, acc0, acc1);
      accum(u3, v3, ad_n, denom, acc0, acc1);
      e += 4;
    }
    for (; e < en; ++e) {
      const int src = G.csr[e];
      const unsigned short u = G.as2[src * NH + head];
      const uint4 hv = G.h2[(size_t)src * NH + head];
      accum(u, hv, ad_n, denom, acc0, acc1);
    }
    // raw barrier: pure phase alignment, no LDS data exchanged -> no drain
    __builtin_amdgcn_s_barrier();
  }
  if (!active) return;
  float inv = 1.f / (denom + 1e-16f);
  const float* bp = G.b + head * NC;
  float4 o0, o1;
  o0.x = acc0.x * inv + bp[0]; o0.y = acc0.y * inv + bp[1];
  o0.z = acc0.z * inv + bp[2]; o0.w = acc0.w * inv + bp[3];
  o1.x = acc1.x * inv + bp[4]; o1.y = acc1.y * inv + bp[5];
  o1.z = acc1.z * inv + bp[6]; o1.w = acc1.w * inv + bp[7];
  float4* op = (float4*)(G.out + (size_t)n * HCH + head * NC);
  op[0] = o0; op[1] = o1;
}

// relu(concat) @ fnn_W + fnn_b -> softmax(2). One wave per node.
__global__ __launch_bounds__(256) void k_fnn(const float* __restrict__ o1,
                                             const float* __restrict__ o2,
                                             const float* __restrict__ o3,
                                             const float* __restrict__ fw,
                                             const float* __restrict__ fb,
                                             float* __restrict__ out) {
  const int tid = blockIdx.x * 256 + threadIdx.x;
  const int n = tid >> 6;
  const int lane = tid & 63;
  if (n >= NN) return;
  float acc0 = 0.f, acc1 = 0.f;
  for (int j = lane; j < 3 * HCH; j += 64) {
    const int g = j / HCH;
    const int c = j - g * HCH;
    const float* og = (g == 0) ? o1 : (g == 1) ? o2 : o3;
    float v = og[(size_t)n * HCH + c];
    v = v > 0.f ? v : 0.f;
    acc0 = fmaf(v, fw[2 * j], acc0);
    acc1 = fmaf(v, fw[2 * j + 1], acc1);
  }
  #pragma unroll
  for (int off = 32; off > 0; off >>= 1) {
    acc0 += __shfl_down(acc0, off, 64);
    acc1 += __shfl_down(acc1, off, 64);
  }
  if (lane == 0) {
    float l0 = acc0 + fb[0], l1 = acc1 + fb[1];
    float m = fmaxf(l0, l1);
    float e0 = __expf(l0 - m), e1 = __expf(l1 - m);
    float inv = 1.f / (e0 + e1);
    out[(size_t)n * 2] = e0 * inv;
    out[(size_t)n * 2 + 1] = e1 * inv;
  }
}

extern "C" void kernel_launch(void* const* d_in, const int* in_sizes, int n_in,
                              void* d_out, int out_size, void* d_ws, size_t ws_size,
                              hipStream_t stream) {
  (void)in_sizes; (void)n_in; (void)out_size; (void)ws_size;
  GT t;
  char* w = (char*)d_ws;
  size_t off = 0;
  auto carve = [&](size_t bytes) -> void* {
    void* p = w + off;
    off = (off + bytes + 255) & ~(size_t)255;
    return p;
  };
  int* bc_all = (int*)carve(3 * NBUCK * BCSTRIDE * 4);   // 3 graphs' padded bcursor
  for (int g = 0; g < 3; ++g) {
    GP& G = t.g[g];
    G.x  = (const float*)d_in[6 * g + 0];
    G.ei = (const int*)d_in[6 * g + 1];     // harness stores int64 inputs as int32
    G.W  = (const float*)d_in[6 * g + 2];
    G.as = (const float*)d_in[6 * g + 3];
    G.ad = (const float*)d_in[6 * g + 4];
    G.b  = (const float*)d_in[6 * g + 5];
    G.bcursor = bc_all + g * NBUCK * BCSTRIDE;
    G.h2   = (uint4*)carve((size_t)NN * NH * 16);
    G.as2  = (unsigned short*)carve((size_t)NN * NH * 2);
    G.a_d  = (float*)carve((size_t)NN * NH * 4);
    G.out  = (float*)carve((size_t)NN * HCH * 4);
    G.wf   = (_Float16*)carve((size_t)4 * 5 * 64 * 8 * 2);
    G.offs2 = (int*)carve((size_t)NBUCK * 256 * NSEG * 4);
    G.pairs = (unsigned int*)carve((size_t)NBUCK * BSTRIDE * 4);
    G.csr   = (int*)carve((size_t)NBUCK * BSTRIDE * 4);
  }
  const float* fw = (const float*)d_in[18];
  const float* fb = (const float*)d_in[19];
  float* outp = (float*)d_out;

  dim3 b256(256, 1, 1);
  hipMemsetAsync(bc_all, 0, 3 * NBUCK * BCSTRIDE * 4, stream);
  k_wpack <<<dim3(1, 1, 3), b256, 0, stream>>>(t);
  k_fat   <<<dim3(BINB + GEMMB2, 1, 3), b256, 0, stream>>>(t);
  k_scat2 <<<dim3(NBUCK, 1, 3), b256, 0, stream>>>(t);
  k_agg   <<<dim3(AGGB * 3, 1, 1), b256, 0, stream>>>(t);
  k_fnn   <<<(NN * 64 + 255) / 256, b256, 0, stream>>>(t.g[0].out, t.g[1].out, t.g[2].out, fw, fb, outp);
}

// Round 11
// 384.239 us; speedup vs baseline: 1.0577x; 1.0577x over previous
//
#include <hip/hip_runtime.h>
#include <hip/hip_fp16.h>

#define NN 50000
#define NE 1600000
#define DD 128
#define NH 9
#define NC 8
#define HCH 72
#define NEG 0.2f
#define NBUCK 196      // ceil(50000/256), 256 dst nodes per bucket
#define NSEG 16        // src segments of 4096 nodes (only 0..12 non-empty)
#define SPAD 17        // padded seg stride in k_scat2 LDS (bank-conflict fix)
#define EPB 16         // edges per thread in bin part
#define BCH (256*EPB)  // 4096 edges per bin block
#define BSTRIDE 10240  // fixed per-bucket capacity (mean 8192, sigma 90 -> +22 sigma)
#define BCSTRIDE 16    // bcursor padded to 64B/bucket
#define GEMMB2 ((NN + 63) / 64)          // 782 mfma-gemm blocks (64 nodes each)
#define BINB ((NE + BCH - 1) / BCH)      // 391 bin blocks
#define AGGB ((NN * NH + 255) / 256)     // 1758 agg blocks per graph
#define CLP 88         // padded col-stride of C LDS tile (fp16)

typedef _Float16 f16x8 __attribute__((ext_vector_type(8)));
typedef float f32x4 __attribute__((ext_vector_type(4)));

__device__ __forceinline__ unsigned short f2h(float f) {
  return __half_as_ushort(__float2half_rn(f));
}
__device__ __forceinline__ float h2f(unsigned short u) {
  return __half2float(__ushort_as_half(u));
}
__device__ __forceinline__ float hlo(unsigned u) {
  return __half2float(__ushort_as_half((unsigned short)(u & 0xFFFFu)));
}
__device__ __forceinline__ float hhi(unsigned u) {
  return __half2float(__ushort_as_half((unsigned short)(u >> 16)));
}

struct GP {
  const float* x; const int* ei; const float* W;
  const float* as; const float* ad; const float* b;
  uint4* h2;                // [NN*9] uint4: 8 fp16 channels per (node,head)
  unsigned short* as2;      // [NN*9] fp16 src-attention scores
  float* a_d; float* out;
  _Float16* wf;             // [4*5*64*8] fragment-ordered fp16 W (20KB, k_wpack)
  int* offs2;               // [NBUCK*256*16] per-(node,seg) absolute csr offsets
  int* bcursor;             // [NBUCK*BCSTRIDE] bucket fill counts (64B-padded, atomic)
  unsigned int* pairs;      // [NBUCK*BSTRIDE] strided bucket runs
  int* csr;                 // [NBUCK*BSTRIDE]
};
struct GT { GP g[3]; };

// Pre-pack W into MFMA B-fragment order, fp16, ONCE per graph. Also zeroes
// bcursor (folded from the former hipMemsetAsync dispatch: one fewer launch).
// wf[((ks*5+ct)*64+lane)*8+j] = fp16(W[ks*32+(lane>>4)*8+j][ct*16+(lane&15)])
__global__ __launch_bounds__(256) void k_wpack(GT t) {
  const GP G = t.g[blockIdx.z];
  const int tid = threadIdx.x;
  for (int i = tid; i < NBUCK * BCSTRIDE; i += 256) G.bcursor[i] = 0;
  for (int idx = tid; idx < 4 * 5 * 64 * 8; idx += 256) {
    const int j = idx & 7;
    const int lane = (idx >> 3) & 63;
    const int ctks = idx >> 9;           // 0..19
    const int ct = ctks % 5;
    const int ks = ctks / 5;
    const int k = ks * 32 + ((lane >> 4) << 3) + j;
    const int col = ct * 16 + (lane & 15);
    const float v = (col < HCH) ? G.W[k * HCH + col] : 0.f;
    G.wf[idx] = (_Float16)v;
  }
}

// Fused bin + gemm (independent stages re-converged so bin's 391 long-pole
// latency blocks (1.5/CU alone) overlap gemm's 782 compute blocks).
// x < BINB: bin edges into fixed-stride bucket runs (LDS sort, coalesced out).
// x >= BINB: h = x@W via MFMA fp16 with pre-packed wf (L2-broadcast B-frags).
__global__ __launch_bounds__(256) void k_fat(GT t) {
  const GP G = t.g[blockIdx.z];
  __shared__ __align__(16) char smem[23072];   // union: bin 23.0KB / gemm 11.3KB
  const int tid = threadIdx.x;

  if (blockIdx.x < BINB) {
    // ---- bin part ----
    unsigned* stage = (unsigned*)smem;                       // 16384 B
    unsigned char* bkt = (unsigned char*)(smem + 16384);     // 4096 B
    int* hist   = (int*)(smem + 20480);                      // 784 B
    int* gdelta = (int*)(smem + 21264);                      // 784 B
    int* ssum   = (int*)(smem + 22048);                      // 1024 B
    const int e0 = blockIdx.x * BCH;

    for (int i = tid; i < NBUCK; i += 256) hist[i] = 0;
    __syncthreads();
    int dsts[EPB], srcs[EPB];
    #pragma unroll
    for (int k = 0; k < EPB; ++k) {
      const int e = e0 + k * 256 + tid;
      if (e < NE) {
        dsts[k] = G.ei[NE + e];
        srcs[k] = G.ei[e];
        atomicAdd(&hist[dsts[k] >> 8], 1);
      } else dsts[k] = -1;
    }
    __syncthreads();
    // exclusive scan over the 196 bucket counts (Hillis-Steele, 256 threads)
    const int cnt_t = (tid < NBUCK) ? hist[tid] : 0;
    ssum[tid] = cnt_t;
    __syncthreads();
    int run = cnt_t;
    for (int off = 1; off < 256; off <<= 1) {
      int u = (tid >= off) ? ssum[tid - off] : 0;
      __syncthreads();
      run += u;
      ssum[tid] = run;
      __syncthreads();
    }
    const int excl = run - cnt_t;
    if (tid < NBUCK) {
      const int gbase = cnt_t ? atomicAdd(&G.bcursor[tid * BCSTRIDE], cnt_t) : 0;
      gdelta[tid] = tid * BSTRIDE + gbase - excl;
      hist[tid] = excl;                  // counts dead; reuse as scatter cursors
    }
    __syncthreads();
    #pragma unroll
    for (int k = 0; k < EPB; ++k) {
      if (dsts[k] >= 0) {
        const int b = dsts[k] >> 8;
        const int pos = atomicAdd(&hist[b], 1);
        stage[pos] = (unsigned)srcs[k] | ((unsigned)(dsts[k] & 255) << 16);
        bkt[pos] = (unsigned char)b;
      }
    }
    __syncthreads();
    const int total = (e0 + BCH <= NE) ? BCH : (NE - e0);
    for (int i = tid; i < total; i += 256) {
      const int b = bkt[i];
      const int addr = gdelta[b] + i;    // = b*BSTRIDE + gbase + (i - lstart[b])
      if (addr - b * BSTRIDE < BSTRIDE)  // overflow guard (effectively never)
        G.pairs[addr] = stage[i];
    }
    return;
  }

  // ---- gemm part ----
  _Float16* Cl = (_Float16*)smem;                      // [64][CLP] 11264 B
  const int wv = tid >> 6;       // wave 0..3 -> rows wv*16..wv*16+15
  const int ln = tid & 63;
  const int rl = ln & 15;        // A row within 16 / B col within 16
  const int kg = ln >> 4;        // k-group 0..3 (8 consecutive k each)
  const int n0 = (blockIdx.x - BINB) << 6;
  int arow = n0 + wv * 16 + rl;
  if (arow >= NN) arow = NN - 1;            // clamp: loads stay in-bounds, stores guarded
  const float4* xr = (const float4*)(G.x + (size_t)arow * DD) + (kg << 1);
  const f16x8* wfp = (const f16x8*)G.wf;

  f32x4 acc[5];
  #pragma unroll
  for (int ct = 0; ct < 5; ++ct) acc[ct] = (f32x4){0.f, 0.f, 0.f, 0.f};

  #pragma unroll
  for (int ks = 0; ks < 4; ++ks) {
    const float4 xa = xr[ks * 8];           // floats kg*8 + ks*32 .. +3
    const float4 xb = xr[ks * 8 + 1];       // .. +7
    float xs[8] = {xa.x, xa.y, xa.z, xa.w, xb.x, xb.y, xb.z, xb.w};
    f16x8 ahi, alo;
    #pragma unroll
    for (int j = 0; j < 8; ++j) {
      const _Float16 h = (_Float16)xs[j];
      ahi[j] = h;
      alo[j] = (_Float16)(xs[j] - (float)h);   // residual: near-fp32 A path
    }
    #pragma unroll
    for (int ct = 0; ct < 5; ++ct) {
      const f16x8 bf = wfp[(ks * 5 + ct) * 64 + ln];
      acc[ct] = __builtin_amdgcn_mfma_f32_16x16x32_f16(ahi, bf, acc[ct], 0, 0, 0);
      acc[ct] = __builtin_amdgcn_mfma_f32_16x16x32_f16(alo, bf, acc[ct], 0, 0, 0);
    }
  }

  // C/D layout (HW-verified): col = lane&15, row = (lane>>4)*4 + reg
  #pragma unroll
  for (int ct = 0; ct < 5; ++ct) {
    #pragma unroll
    for (int j = 0; j < 4; ++j)
      Cl[(wv * 16 + kg * 4 + j) * CLP + ct * 16 + rl] = (_Float16)acc[ct][j];
  }
  __syncthreads();

  // epilogue: per (node,head) pair, h2 is the packed uint4 straight from LDS
  for (int p = tid; p < 64 * NH; p += 256) {
    const int node = p / NH;
    const int hd = p - node * NH;
    const int n = n0 + node;
    if (n >= NN) continue;
    const uint4 hv = *(const uint4*)&Cl[node * CLP + hd * NC];
    const float h0 = hlo(hv.x), h1 = hhi(hv.x), h2v = hlo(hv.y), h3 = hhi(hv.y);
    const float h4 = hlo(hv.z), h5 = hhi(hv.z), h6 = hlo(hv.w), h7 = hhi(hv.w);
    const float4 As0 = *(const float4*)(G.as + hd * NC);
    const float4 As1 = *(const float4*)(G.as + hd * NC + 4);
    const float4 Ad0 = *(const float4*)(G.ad + hd * NC);
    const float4 Ad1 = *(const float4*)(G.ad + hd * NC + 4);
    const float ssrc = h0 * As0.x + h1 * As0.y + h2v * As0.z + h3 * As0.w
                     + h4 * As1.x + h5 * As1.y + h6 * As1.z + h7 * As1.w;
    const float sdst = h0 * Ad0.x + h1 * Ad0.y + h2v * Ad0.z + h3 * Ad0.w
                     + h4 * Ad1.x + h5 * Ad1.y + h6 * Ad1.z + h7 * Ad1.w;
    G.h2[(size_t)n * NH + hd] = hv;
    G.as2[n * NH + hd] = f2h(ssrc);
    G.a_d[n * NH + hd] = sdst;
  }
}

// One block per bucket. LDS counting sort with key (dst_local,seg); sorted
// src values staged in LDS ushort, then coalesced copy-out to csr.
__global__ __launch_bounds__(256) void k_scat2(GT t) {
  const GP G = t.g[blockIdx.z];
  const int b = blockIdx.x;
  const int d0 = b << 8;
  __shared__ int cnt[256 * SPAD];            // 17.4 KB (counts, then LOCAL cursors)
  __shared__ int ssum[256];
  __shared__ unsigned short stage[BSTRIDE];  // 20.5 KB sorted src values
  const int tid = threadIdx.x;
  const int estart = b * BSTRIDE;
  const int count0 = G.bcursor[b * BCSTRIDE];
  const int count = (count0 < BSTRIDE) ? count0 : BSTRIDE;   // clamp (never in practice)
  const int eend = estart + count;
  for (int i = tid; i < 256 * SPAD; i += 256) cnt[i] = 0;
  __syncthreads();
  for (int e = estart + tid; e < eend; e += 256) {
    unsigned p = G.pairs[e];
    int key = (int)((p >> 16) * SPAD + ((p & 0xFFFFu) >> 12));
    atomicAdd(&cnt[key], 1);
  }
  __syncthreads();
  int local[NSEG];
  int sum = 0;
  #pragma unroll
  for (int i = 0; i < NSEG; ++i) { local[i] = sum; sum += cnt[tid * SPAD + i]; }
  ssum[tid] = sum;
  __syncthreads();
  int run = sum;
  for (int off = 1; off < 256; off <<= 1) {
    int u = (tid >= off) ? ssum[tid - off] : 0;
    __syncthreads();
    run += u;
    ssum[tid] = run;
    __syncthreads();
  }
  const int texcl = run - sum;
  int* o2 = G.offs2 + ((size_t)d0 << 4);
  #pragma unroll
  for (int i = 0; i < NSEG; ++i) {
    const int v = texcl + local[i];         // bucket-LOCAL offset
    cnt[tid * SPAD + i] = v;                // counts dead; reuse as local cursors
    o2[tid * NSEG + i] = estart + v;        // offs2 stays ABSOLUTE
  }
  __syncthreads();
  for (int e = estart + tid; e < eend; e += 256) {
    unsigned p = G.pairs[e];
    int key = (int)((p >> 16) * SPAD + ((p & 0xFFFFu) >> 12));
    int lpos = atomicAdd(&cnt[key], 1);
    if (lpos < BSTRIDE)
      stage[lpos] = (unsigned short)(p & 0xFFFFu);
  }
  __syncthreads();
  // coalesced copy-out: dense sequential 4B stores -> full-line writebacks
  for (int i = tid; i < count; i += 256)
    G.csr[estart + i] = (int)stage[i];
}

// gather aggregation: thread (dst,head), barrier every 4 src-segments,
// 4-edge batched loads. All 3 graphs fused, GRAPH-MAJOR block order.
// (R10's 8-batch + raw-barrier variant regressed 133->154; this is the
// R9/R4-proven form, measured 133.4us three times.)
__global__ __launch_bounds__(256) void k_agg(GT t) {
  const int g = blockIdx.x / AGGB;
  const GP G = t.g[g];
  const int gid = (blockIdx.x - g * AGGB) * 256 + threadIdx.x;
  const bool active = (gid < NN * NH);
  int n = 0, head = 0;
  if (active) { n = gid / NH; head = gid - n * NH; }
  float denom = 0.f;
  float4 acc0 = make_float4(0.f, 0.f, 0.f, 0.f);
  float4 acc1 = make_float4(0.f, 0.f, 0.f, 0.f);
  float ad_n = 0.f;
  int gb[5] = {0, 0, 0, 0, 0};
  if (active) {
    ad_n = G.a_d[n * NH + head];
    const int* o2 = G.offs2 + ((size_t)n << 4);
    gb[0] = o2[0]; gb[1] = o2[4]; gb[2] = o2[8]; gb[3] = o2[12]; gb[4] = o2[13];
    float sl = h2f(G.as2[n * NH + head]) + ad_n;
    sl = (sl > 0.f) ? sl : NEG * sl;
    float wl = __expf(sl);
    uint4 hs = G.h2[(size_t)n * NH + head];
    denom = wl;
    acc0.x = wl * hlo(hs.x); acc0.y = wl * hhi(hs.x);
    acc0.z = wl * hlo(hs.y); acc0.w = wl * hhi(hs.y);
    acc1.x = wl * hlo(hs.z); acc1.y = wl * hhi(hs.z);
    acc1.z = wl * hlo(hs.w); acc1.w = wl * hhi(hs.w);
  }
  #pragma unroll
  for (int sgrp = 0; sgrp < 4; ++sgrp) {
    int e = gb[sgrp];
    const int en = gb[sgrp + 1];
    for (; e + 4 <= en; e += 4) {
      int s0 = G.csr[e];
      int s1 = G.csr[e + 1];
      int s2 = G.csr[e + 2];
      int s3 = G.csr[e + 3];
      unsigned short u0 = G.as2[s0 * NH + head];
      unsigned short u1 = G.as2[s1 * NH + head];
      unsigned short u2 = G.as2[s2 * NH + head];
      unsigned short u3 = G.as2[s3 * NH + head];
      uint4 v0 = G.h2[(size_t)s0 * NH + head];
      uint4 v1 = G.h2[(size_t)s1 * NH + head];
      uint4 v2 = G.h2[(size_t)s2 * NH + head];
      uint4 v3 = G.h2[(size_t)s3 * NH + head];
      float t0 = h2f(u0) + ad_n;
      float t1 = h2f(u1) + ad_n;
      float t2 = h2f(u2) + ad_n;
      float t3 = h2f(u3) + ad_n;
      t0 = (t0 > 0.f) ? t0 : NEG * t0;
      t1 = (t1 > 0.f) ? t1 : NEG * t1;
      t2 = (t2 > 0.f) ? t2 : NEG * t2;
      t3 = (t3 > 0.f) ? t3 : NEG * t3;
      float w0 = __expf(t0);
      float w1 = __expf(t1);
      float w2 = __expf(t2);
      float w3 = __expf(t3);
      denom += (w0 + w1) + (w2 + w3);
      acc0.x = fmaf(w0, hlo(v0.x), acc0.x); acc0.y = fmaf(w0, hhi(v0.x), acc0.y);
      acc0.z = fmaf(w0, hlo(v0.y), acc0.z); acc0.w = fmaf(w0, hhi(v0.y), acc0.w);
      acc1.x = fmaf(w0, hlo(v0.z), acc1.x); acc1.y = fmaf(w0, hhi(v0.z), acc1.y);
      acc1.z = fmaf(w0, hlo(v0.w), acc1.z); acc1.w = fmaf(w0, hhi(v0.w), acc1.w);
      acc0.x = fmaf(w1, hlo(v1.x), acc0.x); acc0.y = fmaf(w1, hhi(v1.x), acc0.y);
      acc0.z = fmaf(w1, hlo(v1.y), acc0.z); acc0.w = fmaf(w1, hhi(v1.y), acc0.w);
      acc1.x = fmaf(w1, hlo(v1.z), acc1.x); acc1.y = fmaf(w1, hhi(v1.z), acc1.y);
      acc1.z = fmaf(w1, hlo(v1.w), acc1.z); acc1.w = fmaf(w1, hhi(v1.w), acc1.w);
      acc0.x = fmaf(w2, hlo(v2.x), acc0.x); acc0.y = fmaf(w2, hhi(v2.x), acc0.y);
      acc0.z = fmaf(w2, hlo(v2.y), acc0.z); acc0.w = fmaf(w2, hhi(v2.y), acc0.w);
      acc1.x = fmaf(w2, hlo(v2.z), acc1.x); acc1.y = fmaf(w2, hhi(v2.z), acc1.y);
      acc1.z = fmaf(w2, hlo(v2.w), acc1.z); acc1.w = fmaf(w2, hhi(v2.w), acc1.w);
      acc0.x = fmaf(w3, hlo(v3.x), acc0.x); acc0.y = fmaf(w3, hhi(v3.x), acc0.y);
      acc0.z = fmaf(w3, hlo(v3.y), acc0.z); acc0.w = fmaf(w3, hhi(v3.y), acc0.w);
      acc1.x = fmaf(w3, hlo(v3.z), acc1.x); acc1.y = fmaf(w3, hhi(v3.z), acc1.y);
      acc1.z = fmaf(w3, hlo(v3.w), acc1.z); acc1.w = fmaf(w3, hhi(v3.w), acc1.w);
    }
    for (; e < en; ++e) {
      int src = G.csr[e];
      float sc = h2f(G.as2[src * NH + head]) + ad_n;
      sc = (sc > 0.f) ? sc : NEG * sc;
      float w = __expf(sc);
      uint4 hv = G.h2[(size_t)src * NH + head];
      denom += w;
      acc0.x = fmaf(w, hlo(hv.x), acc0.x); acc0.y = fmaf(w, hhi(hv.x), acc0.y);
      acc0.z = fmaf(w, hlo(hv.y), acc0.z); acc0.w = fmaf(w, hhi(hv.y), acc0.w);
      acc1.x = fmaf(w, hlo(hv.z), acc1.x); acc1.y = fmaf(w, hhi(hv.z), acc1.y);
      acc1.z = fmaf(w, hlo(hv.w), acc1.z); acc1.w = fmaf(w, hhi(hv.w), acc1.w);
    }
    __syncthreads();
  }
  if (!active) return;
  float inv = 1.f / (denom + 1e-16f);
  const float* bp = G.b + head * NC;
  float4 o0, o1;
  o0.x = acc0.x * inv + bp[0]; o0.y = acc0.y * inv + bp[1];
  o0.z = acc0.z * inv + bp[2]; o0.w = acc0.w * inv + bp[3];
  o1.x = acc1.x * inv + bp[4]; o1.y = acc1.y * inv + bp[5];
  o1.z = acc1.z * inv + bp[6]; o1.w = acc1.w * inv + bp[7];
  float4* op = (float4*)(G.out + (size_t)n * HCH + head * NC);
  op[0] = o0; op[1] = o1;
}

// relu(concat) @ fnn_W + fnn_b -> softmax(2). One wave per node.
__global__ __launch_bounds__(256) void k_fnn(const float* __restrict__ o1,
                                             const float* __restrict__ o2,
                                             const float* __restrict__ o3,
                                             const float* __restrict__ fw,
                                             const float* __restrict__ fb,
                                             float* __restrict__ out) {
  const int tid = blockIdx.x * 256 + threadIdx.x;
  const int n = tid >> 6;
  const int lane = tid & 63;
  if (n >= NN) return;
  float acc0 = 0.f, acc1 = 0.f;
  for (int j = lane; j < 3 * HCH; j += 64) {
    const int g = j / HCH;
    const int c = j - g * HCH;
    const float* og = (g == 0) ? o1 : (g == 1) ? o2 : o3;
    float v = og[(size_t)n * HCH + c];
    v = v > 0.f ? v : 0.f;
    acc0 = fmaf(v, fw[2 * j], acc0);
    acc1 = fmaf(v, fw[2 * j + 1], acc1);
  }
  #pragma unroll
  for (int off = 32; off > 0; off >>= 1) {
    acc0 += __shfl_down(acc0, off, 64);
    acc1 += __shfl_down(acc1, off, 64);
  }
  if (lane == 0) {
    float l0 = acc0 + fb[0], l1 = acc1 + fb[1];
    float m = fmaxf(l0, l1);
    float e0 = __expf(l0 - m), e1 = __expf(l1 - m);
    float inv = 1.f / (e0 + e1);
    out[(size_t)n * 2] = e0 * inv;
    out[(size_t)n * 2 + 1] = e1 * inv;
  }
}

extern "C" void kernel_launch(void* const* d_in, const int* in_sizes, int n_in,
                              void* d_out, int out_size, void* d_ws, size_t ws_size,
                              hipStream_t stream) {
  (void)in_sizes; (void)n_in; (void)out_size; (void)ws_size;
  GT t;
  char* w = (char*)d_ws;
  size_t off = 0;
  auto carve = [&](size_t bytes) -> void* {
    void* p = w + off;
    off = (off + bytes + 255) & ~(size_t)255;
    return p;
  };
  int* bc_all = (int*)carve(3 * NBUCK * BCSTRIDE * 4);   // 3 graphs' padded bcursor
  for (int g = 0; g < 3; ++g) {
    GP& G = t.g[g];
    G.x  = (const float*)d_in[6 * g + 0];
    G.ei = (const int*)d_in[6 * g + 1];     // harness stores int64 inputs as int32
    G.W  = (const float*)d_in[6 * g + 2];
    G.as = (const float*)d_in[6 * g + 3];
    G.ad = (const float*)d_in[6 * g + 4];
    G.b  = (const float*)d_in[6 * g + 5];
    G.bcursor = bc_all + g * NBUCK * BCSTRIDE;
    G.h2   = (uint4*)carve((size_t)NN * NH * 16);
    G.as2  = (unsigned short*)carve((size_t)NN * NH * 2);
    G.a_d  = (float*)carve((size_t)NN * NH * 4);
    G.out  = (float*)carve((size_t)NN * HCH * 4);
    G.wf   = (_Float16*)carve((size_t)4 * 5 * 64 * 8 * 2);
    G.offs2 = (int*)carve((size_t)NBUCK * 256 * NSEG * 4);
    G.pairs = (unsigned int*)carve((size_t)NBUCK * BSTRIDE * 4);
    G.csr   = (int*)carve((size_t)NBUCK * BSTRIDE * 4);
  }
  const float* fw = (const float*)d_in[18];
  const float* fb = (const float*)d_in[19];
  float* outp = (float*)d_out;

  dim3 b256(256, 1, 1);
  k_wpack <<<dim3(1, 1, 3), b256, 0, stream>>>(t);
  k_fat   <<<dim3(BINB + GEMMB2, 1, 3), b256, 0, stream>>>(t);
  k_scat2 <<<dim3(NBUCK, 1, 3), b256, 0, stream>>>(t);
  k_agg   <<<dim3(AGGB * 3, 1, 1), b256, 0, stream>>>(t);
  k_fnn   <<<(NN * 64 + 255) / 256, b256, 0, stream>>>(t.g[0].out, t.g[1].out, t.g[2].out, fw, fb, outp);
}